// Round 7
// baseline (115.008 us; speedup 1.0000x reference)
//
#include <hip/hip_runtime.h>
#include <hip/hip_bf16.h>

// Problem constants (from reference)
#define MAX_LEN_PAD 2560
#define MIN_LEN_SEG 19
#define MAX_NUM_SEG 108   // segments per batch row
#define B_ROWS      32
#define S_CAND      64
#define N_SEG       3456  // B_ROWS * MAX_NUM_SEG

// ws layout (ints)
#define WS_META   0        // [0]=rows, [1]=M
#define WS_TABLE  8192     // int2 per output row: 81920 entries

// K1: single block, 1024 threads, one dispatch does everything except the
// final gather. Threads 0..575 own 6 consecutive segments each (18 thr per
// batch row — row starts align to thread boundaries):
//   scan1: global cumsum of len_seg -> per-segment in-row offsets
//   counts: mask is a prefix in s -> 6-step binsearch w/ the reference's
//           exact IEEE fp32 predicate
//   scan2: global exclusive scan of counts -> seg_start (into LDS)
// Then ALL 1024 threads fill the (src_row, lam) table: the compaction is a
// bijection, segment n element s lands at g=seg_start[n]+s -> out row
// (g/rows, g%rows). Table is ~262 KB -> L2. Slots t>=M stay unwritten (unread).
__global__ __launch_bounds__(1024) void k1_all(
    const int* __restrict__ len_seq, const float* __restrict__ scales_u,
    const int* __restrict__ len_seg_raw, int* __restrict__ ws)
{
    __shared__ int   s_part[16];
    __shared__ int   s_rowcum[B_ROWS];
    __shared__ int   s_misc[2];            // rows, M
    __shared__ int   s_start[N_SEG + 1];
    __shared__ int   s_off[N_SEG];
    __shared__ float s_scale[N_SEG];

    const int tid    = threadIdx.x;
    const int lane   = tid & 63;
    const int wave   = tid >> 6;           // 0..15
    const bool active = tid < N_SEG / 6;   // 576 scan threads
    const int brow   = tid / 18;           // batch row of this thread's 6 segs

    // ---- load 6 segments/thread ----
    int v[6]; float sc[6]; int sum = 0;
    if (active) {
        #pragma unroll
        for (int j = 0; j < 6; ++j) {
            int k = tid * 6 + j;
            v[j]  = len_seg_raw[k] + MIN_LEN_SEG;
            sc[j] = scales_u[k];
            sum  += v[j];
        }
    }

    // ---- scan1: global exclusive cumsum of lenseg ----
    int incl = sum;
    #pragma unroll
    for (int d = 1; d < 64; d <<= 1) {
        int o = __shfl_up(incl, d, 64);
        if (lane >= d) incl += o;
    }
    if (lane == 63) s_part[wave] = incl;
    __syncthreads();                                    // B1
    if (tid == 0) {
        int run = 0;
        #pragma unroll
        for (int w = 0; w < 16; ++w) { int p = s_part[w]; s_part[w] = run; run += p; }
    }
    __syncthreads();                                    // B2
    const int gbase = s_part[wave] + incl - sum;
    if (active && (tid % 18 == 0)) s_rowcum[brow] = gbase;  // row starts align
    __syncthreads();                                    // B3

    // ---- per-segment offsets + counts (exact fp32 predicate) ----
    int cnt[6]; int csum = 0; int offv[6];
    if (active) {
        const int ls   = len_seq[brow];
        const int rowc = s_rowcum[brow];
        int run = gbase;
        #pragma unroll
        for (int j = 0; j < 6; ++j) {
            int off = run - rowc;
            offv[j] = off;
            run += v[j];
            float scale = sc[j] + 0.5f;
            int T = v[j] - 1;
            int lim = ls - 1 - off;
            if (lim < T) T = lim;
            float Tf = (float)T;
            int lo = 0, hi = S_CAND;
            while (lo < hi) {
                int mid = (lo + hi) >> 1;
                // exact IEEE div + floor: bitwise-matches reference predicate
                if (floorf((float)mid / scale) < Tf) lo = mid + 1; else hi = mid;
            }
            cnt[j] = lo; csum += lo;
        }
    }

    // ---- scan2: global exclusive scan of counts ----
    int cincl = csum;
    #pragma unroll
    for (int d = 1; d < 64; d <<= 1) {
        int o = __shfl_up(cincl, d, 64);
        if (lane >= d) cincl += o;
    }
    if (lane == 63) s_part[wave] = cincl;
    __syncthreads();                                    // B4
    if (tid == 0) {
        int run = 0;
        #pragma unroll
        for (int w = 0; w < 16; ++w) { int p = s_part[w]; s_part[w] = run; run += p; }
        int total = run;
        int rows = total / B_ROWS;
        int M = rows < MAX_LEN_PAD ? rows : MAX_LEN_PAD;
        s_misc[0] = rows; s_misc[1] = M;
        ws[WS_META + 0] = rows;
        ws[WS_META + 1] = M;
        s_start[N_SEG] = total;
    }
    __syncthreads();                                    // B5
    if (active) {
        int run = s_part[wave] + cincl - csum;
        #pragma unroll
        for (int j = 0; j < 6; ++j) {
            int k = tid * 6 + j;
            s_start[k] = run; run += cnt[j];
            s_off[k]   = offv[j];
            s_scale[k] = sc[j];
        }
    }
    __syncthreads();                                    // B6

    // ---- table fill: all 1024 threads over (segment x 16-elem chunk) ----
    const int rows = s_misc[0];
    if (rows > 0) {
        int2* table = (int2*)(ws + WS_TABLE);
        for (int u = tid; u < N_SEG * 4; u += 1024) {
            int n  = u >> 2;
            int c0 = (u & 3) << 4;
            int st = s_start[n];
            int cn = s_start[n + 1] - st;
            if (c0 >= cn) continue;
            int smax = cn < c0 + 16 ? cn : c0 + 16;
            float scale = s_scale[n] + 0.5f;
            int off     = s_off[n];
            int srcbase = (n / MAX_NUM_SEG) * MAX_LEN_PAD;
            int g  = st + c0;
            int bo = g / rows;              // one div per 16-elem chunk
            int t  = g - bo * rows;
            for (int s = c0; s < smax; ++s) {
                if (bo < B_ROWS && t < MAX_LEN_PAD) {
                    float q  = (float)s / scale;     // exact IEEE, matches ref
                    float fi = floorf(q);
                    float lam = q - fi;
                    int i_fl = (int)fi + off;
                    if (i_fl > MAX_LEN_PAD - 2) i_fl = MAX_LEN_PAD - 2;  // ref clip
                    table[bo * MAX_LEN_PAD + t] =
                        make_int2(srcbase + i_fl, __float_as_int(lam));
                }
                if (++t >= rows) { t = 0; ++bo; }
            }
        }
    }
}

// K3: pure gather — no searches, no barriers, no LDS. 2560 blocks x 640 thr,
// one float4 per thread. The 20 lanes of an output row broadcast-read the
// same 8-B table entry (L1), then do coalesced float4 lerp / zero.
__global__ __launch_bounds__(640) void k3_gather(
    const float* __restrict__ x, const int* __restrict__ ws,
    float* __restrict__ out)
{
    const int M = ws[WS_META + 1];
    int flat = blockIdx.x * 640 + threadIdx.x;   // = r*20 + q4
    int r  = flat / 20;                          // magic-mul div
    int q4 = flat - r * 20;
    int t  = r % MAX_LEN_PAD;                    // magic-mul mod

    float4 res = make_float4(0.f, 0.f, 0.f, 0.f);
    if (t < M) {
        int2 e = ((const int2*)(ws + WS_TABLE))[r];
        int src = e.x;
        float lam = __int_as_float(e.y);
        const float4* x4 = (const float4*)x;
        float4 a = x4[src * 20 + q4];
        float4 c = x4[src * 20 + 20 + q4];
        float om = 1.0f - lam;
        res.x = om * a.x + lam * c.x;
        res.y = om * a.y + lam * c.y;
        res.z = om * a.z + lam * c.z;
        res.w = om * a.w + lam * c.w;
    }
    ((float4*)out)[flat] = res;
}

extern "C" void kernel_launch(void* const* d_in, const int* in_sizes, int n_in,
                              void* d_out, int out_size, void* d_ws, size_t ws_size,
                              hipStream_t stream) {
    (void)in_sizes; (void)n_in; (void)out_size; (void)ws_size;
    const float* x           = (const float*)d_in[0];
    const int*   len_seq     = (const int*)d_in[1];
    const float* scales_u    = (const float*)d_in[2];
    const int*   len_seg_raw = (const int*)d_in[3];
    float* out = (float*)d_out;
    int*   ws  = (int*)d_ws;

    k1_all<<<1, 1024, 0, stream>>>(len_seq, scales_u, len_seg_raw, ws);
    k3_gather<<<2560, 640, 0, stream>>>(x, ws, out);
}